// Round 4
// baseline (677.123 us; speedup 1.0000x reference)
//
#include <hip/hip_runtime.h>
#include <hip/hip_bf16.h>
#include <math.h>

#define NTOK  32768
#define GNEPS 1e-5f

typedef __attribute__((ext_vector_type(4))) float f32x4;
typedef __attribute__((ext_vector_type(8))) short s16x8;
typedef __attribute__((ext_vector_type(4))) unsigned short u16x4;

__device__ __forceinline__ unsigned short f2b(float f) {
  unsigned int u = __float_as_uint(f);
  unsigned int r = (u + 0x7FFFu + ((u >> 16) & 1u)) >> 16;
  return (unsigned short)r;
}
__device__ __forceinline__ float b2f(unsigned short s) {
  return __uint_as_float(((unsigned int)s) << 16);
}
// order-preserving float<->uint for atomicMax
__device__ __forceinline__ unsigned int fenc(float f) {
  unsigned int u = __float_as_uint(f);
  return (u & 0x80000000u) ? ~u : (u | 0x80000000u);
}
__device__ __forceinline__ float fdec(unsigned int k) {
  unsigned int u = (k & 0x80000000u) ? (k ^ 0x80000000u) : ~k;
  return __uint_as_float(u);
}

__device__ __forceinline__ void stage16(const unsigned short* g, unsigned short* ldsChunkBase, int lane) {
#if __has_builtin(__builtin_amdgcn_global_load_lds)
  __builtin_amdgcn_global_load_lds((const __attribute__((address_space(1))) void*)g,
                                   (__attribute__((address_space(3))) void*)ldsChunkBase, 16, 0, 0);
#else
  *(s16x8*)((char*)ldsChunkBase + lane * 16) = *(const s16x8*)g;
#endif
}

// ---- workspace layout (bytes) ----
#define OFF_GSTAT   0u                // 32 f32
#define OFF_KMK     128u              // 1024 u32 encoded k row max
#define OFF_SSUM    4224u             // 1024 f32 k-softmax denominators
#define OFF_CTX     8320u             // 4*8*32*32 f32 = 131072 (unnormalized)
#define OFF_WCTXB   139392u           // 4*256*256 bf16 = 524288
#define OFF_BIASP   663680u           // 4*768 f32 = 12288
#define OFF_WP      675968u           // 4*768*256 bf16 = 1572864
#define OFF_XT      2248832u          // 4*32768*256 bf16 = 67108864 (raw x, [n][c])
#define OFF_QT      69357696u         // 4*32768*256 bf16 = 67108864
#define OFF_KVB     136466560u        // 4*512*32768 bf16 = 134217728
#define WS_NEEDED   (OFF_KVB + 134217728ull)

// ------------------------------------------------------------------
// K1: fused GN stats + raw-x bf16 cast + transpose -> xT [b][n][c]
// grid (512 n-tiles of 64, 4 b), 256 thr
// ------------------------------------------------------------------
__global__ __launch_bounds__(256) void gn_fused(const float* __restrict__ x,
                                                float* __restrict__ gstat,
                                                unsigned short* __restrict__ xT) {
  __shared__ unsigned short s1[256 * 68];
  __shared__ float rs[4][4], rq[4][4];
  int b = blockIdx.y;
  int n0 = blockIdx.x * 64;
  int tid = threadIdx.x;
  const float* xb = x + (size_t)b * 256 * NTOK;
  float s[4] = {0.f, 0.f, 0.f, 0.f}, sq[4] = {0.f, 0.f, 0.f, 0.f};
#pragma unroll
  for (int it = 0; it < 16; ++it) {
    int idx = tid + it * 256;          // 4096 = 256c x 16 quads
    int c = idx >> 4, q = idx & 15;
    f32x4 v = *reinterpret_cast<const f32x4*>(&xb[(size_t)c * NTOK + n0 + q * 4]);
    const int g = it >> 2;             // compile-time
    s[g]  += v.x + v.y + v.z + v.w;
    sq[g] += v.x * v.x + v.y * v.y + v.z * v.z + v.w * v.w;
    u16x4 o = { f2b(v.x), f2b(v.y), f2b(v.z), f2b(v.w) };
    *reinterpret_cast<u16x4*>(&s1[c * 68 + q * 4]) = o;
  }
  int lane = tid & 63, w = tid >> 6;
#pragma unroll
  for (int g = 0; g < 4; ++g) {
    float a = s[g], bq = sq[g];
    for (int o = 32; o > 0; o >>= 1) { a += __shfl_down(a, o); bq += __shfl_down(bq, o); }
    if (lane == 0) { rs[w][g] = a; rq[w][g] = bq; }
  }
  __syncthreads();
  if (tid < 8) {
    int g = tid >> 1, part = tid & 1;
    float v = part ? (rq[0][g] + rq[1][g] + rq[2][g] + rq[3][g])
                   : (rs[0][g] + rs[1][g] + rs[2][g] + rs[3][g]);
    atomicAdd(&gstat[2 * (b * 4 + g) + part], v);
  }
#pragma unroll
  for (int it = 0; it < 8; ++it) {
    int task = tid + it * 256;         // 2048 = 64n x 32 octets
    int n = task >> 5, oc = task & 31;
    s16x8 pk;
#pragma unroll
    for (int i = 0; i < 8; ++i) pk[i] = (short)s1[(oc * 8 + i) * 68 + n];
    *reinterpret_cast<s16x8*>(&xT[((size_t)(b * NTOK + n0 + n)) * 256 + oc * 8]) = pk;
  }
}

// ------------------------------------------------------------------
// K2: finalize stats + fold GN into weights.
// grid (768 o, 4 b), 256 thr (one per c)
// Wp[b][o][c] = bf16(W[o][c]*gamma[c]*rsig);  biasp[b][o] = sum_c W*(beta-mu*gamma*rsig)
// ------------------------------------------------------------------
__global__ __launch_bounds__(256) void fold_w(const float* __restrict__ wqkv,
                                              const float* __restrict__ gamma,
                                              const float* __restrict__ beta,
                                              const float* __restrict__ gstat,
                                              unsigned short* __restrict__ Wp,
                                              float* __restrict__ biasp) {
  int o = blockIdx.x, b = blockIdx.y;
  int c = threadIdx.x;
  int g = c >> 6;
  const float cnt = 64.f * (float)NTOK;
  float mu  = gstat[2 * (b * 4 + g)] / cnt;
  float var = gstat[2 * (b * 4 + g) + 1] / cnt - mu * mu;
  float rsig = rsqrtf(var + GNEPS);
  float wv = wqkv[(size_t)o * 256 + c];
  float A = gamma[c] * rsig;
  float Bc = beta[c] - mu * A;
  Wp[((size_t)b * 768 + o) * 256 + c] = f2b(wv * A);
  float t = wv * Bc;
  int lane = c & 63, w = c >> 6;
  for (int off = 32; off > 0; off >>= 1) t += __shfl_down(t, off);
  __shared__ float red[4];
  if (lane == 0) red[w] = t;
  __syncthreads();
  if (c == 0) biasp[b * 768 + o] = red[0] + red[1] + red[2] + red[3];
}

// ------------------------------------------------------------------
// K3: qkv GEMM. Block = (b, 64n), ALL 768 o in 3 passes of 256.
// B (xT tile) resident in LDS (staged once, swizzled); A streamed from L2.
// Barrier-free K loop. Epilogue: bias add; q -> qT[n][o], k/v -> kvb[row][n];
// k rows also atomicMax row-max (encoded).
// ------------------------------------------------------------------
__global__ __launch_bounds__(256) void qkv_gemm(const unsigned short* __restrict__ Wp,
                                                const float* __restrict__ biasp,
                                                const unsigned short* __restrict__ xT,
                                                unsigned short* __restrict__ qT,
                                                unsigned short* __restrict__ kvb,
                                                unsigned int* __restrict__ kmk) {
  __shared__ unsigned short Bs[64 * 256];     // 32KB [n][c], 16B blocks xor-swizzled
  __shared__ unsigned short bounce[64 * 72];  // 9.2KB epilogue bounce
  int bid = blockIdx.x;
  int L = (bid & 7) * 256 + (bid >> 3);       // 2048 = 8*256, bijective
  int b = L >> 9, ntile = L & 511;
  int n0 = ntile * 64;
  int tid = threadIdx.x;
  int w = tid >> 6, l = tid & 63;
  int hi = l >> 4, lo = l & 15;

  // ---- stage B once: 32 chunks of 1KB, 8 per wave ----
  const unsigned short* xb = xT + ((size_t)(b * NTOK + n0)) * 256;
  {
    int lr = l >> 5, lj = l & 31;
#pragma unroll
    for (int q = 0; q < 8; ++q) {
      int chunk = w * 8 + q;
      int row = chunk * 2 + lr;
      int srcslot = lj ^ (row & 7);
      stage16(xb + (size_t)row * 256 + srcslot * 8, Bs + chunk * 512, l);
    }
  }
  __syncthreads();

  for (int p = 0; p < 3; ++p) {
    f32x4 acc[4][4];
#pragma unroll
    for (int s = 0; s < 4; ++s)
#pragma unroll
      for (int nt = 0; nt < 4; ++nt) acc[s][nt] = (f32x4){0.f, 0.f, 0.f, 0.f};

    const unsigned short* Ab = Wp + ((size_t)(b * 768 + p * 256 + w * 64)) * 256;
#pragma unroll
    for (int t = 0; t < 8; ++t) {
      s16x8 af[4], bf[4];
#pragma unroll
      for (int s = 0; s < 4; ++s)
        af[s] = *reinterpret_cast<const s16x8*>(&Ab[(size_t)(s * 16 + lo) * 256 + t * 32 + hi * 8]);
#pragma unroll
      for (int nt = 0; nt < 4; ++nt) {
        int r = nt * 16 + lo;
        int phys = (t * 4 + hi) ^ (r & 7);
        bf[nt] = *reinterpret_cast<const s16x8*>(&Bs[r * 256 + phys * 8]);
      }
#pragma unroll
      for (int s = 0; s < 4; ++s)
#pragma unroll
        for (int nt = 0; nt < 4; ++nt)
          acc[s][nt] = __builtin_amdgcn_mfma_f32_16x16x32_bf16(af[s], bf[nt], acc[s][nt], 0, 0, 0);
    }

    // bias add
#pragma unroll
    for (int s = 0; s < 4; ++s)
#pragma unroll
      for (int i = 0; i < 4; ++i) {
        float bv = biasp[b * 768 + p * 256 + w * 64 + s * 16 + hi * 4 + i];
#pragma unroll
        for (int nt = 0; nt < 4; ++nt) acc[s][nt][i] += bv;
      }

    // k row max (pass 1 holds o in [256,512) => k rows 0..255)
    if (p == 1) {
#pragma unroll
      for (int s = 0; s < 4; ++s)
#pragma unroll
        for (int i = 0; i < 4; ++i) {
          float m = fmaxf(fmaxf(acc[s][0][i], acc[s][1][i]), fmaxf(acc[s][2][i], acc[s][3][i]));
          m = fmaxf(m, __shfl_xor(m, 1));
          m = fmaxf(m, __shfl_xor(m, 2));
          m = fmaxf(m, __shfl_xor(m, 4));
          m = fmaxf(m, __shfl_xor(m, 8));
          if (lo == 0)
            atomicMax(&kmk[b * 256 + w * 64 + s * 16 + hi * 4 + i], fenc(m));
        }
    }

    // epilogue: 4 chunks (one per wave), LDS bounce -> coalesced 16B stores
    for (int ch = 0; ch < 4; ++ch) {
      __syncthreads();
      if (w == ch) {
#pragma unroll
        for (int s = 0; s < 4; ++s)
#pragma unroll
          for (int nt = 0; nt < 4; ++nt)
#pragma unroll
            for (int i = 0; i < 4; ++i) {
              int o_l = s * 16 + hi * 4 + i;
              int n_l = nt * 16 + lo;
              if (p == 0) bounce[n_l * 72 + o_l] = f2b(acc[s][nt][i]);
              else        bounce[o_l * 72 + n_l] = f2b(acc[s][nt][i]);
            }
      }
      __syncthreads();
#pragma unroll
      for (int it = 0; it < 2; ++it) {
        int task = tid + it * 256;           // 512 = 64 rows x 8 slots
        int rr = task >> 3, j = task & 7;
        s16x8 v = *reinterpret_cast<const s16x8*>(&bounce[rr * 72 + j * 8]);
        if (p == 0)
          *reinterpret_cast<s16x8*>(&qT[((size_t)(b * NTOK + n0 + rr)) * 256 + ch * 64 + j * 8]) = v;
        else
          *reinterpret_cast<s16x8*>(&kvb[((size_t)(b * 512 + (p - 1) * 256 + ch * 64 + rr)) * NTOK + n0 + j * 8]) = v;
      }
    }
  }
}

// ------------------------------------------------------------------
// K4: ctx~[b][h][d][e] += sum_n exp(k-kmax)[d][n] * v[e][n];  S[b][h][d] += sum_n exp
// grid (32 n-chunks of 1024, 32 bh), 256 thr
// ------------------------------------------------------------------
__global__ __launch_bounds__(256) void context_partial(const unsigned short* __restrict__ kvb,
                                                       const unsigned int* __restrict__ kmk,
                                                       float* __restrict__ ctx,
                                                       float* __restrict__ Ssum) {
  int bh = blockIdx.y;
  int b = bh >> 3, h = bh & 7;
  int n0 = blockIdx.x * 1024;
  const unsigned short* kb = kvb + ((size_t)(b * 512) + h * 32) * NTOK;
  const unsigned short* vb = kvb + ((size_t)(b * 512) + 256 + h * 32) * NTOK;
  __shared__ float kt[32][260];
  __shared__ float vt[32][260];
  int tid = threadIdx.x;
  int d2 = (tid >> 4) * 2;
  int e2 = (tid & 15) * 2;
  int rbase = b * 256 + h * 32;
  float acc[2][2] = {};
  float psum[4] = {0.f, 0.f, 0.f, 0.f};
  for (int sub = 0; sub < 4; ++sub) {
    int nb = n0 + sub * 256;
    __syncthreads();
#pragma unroll
    for (int it = 0; it < 4; ++it) {
      int u = tid + it * 256;
      int d = u >> 5, oc = u & 31;
      float km = fdec(kmk[rbase + d]);
      s16x8 kv = *reinterpret_cast<const s16x8*>(&kb[(size_t)d * NTOK + nb + oc * 8]);
      s16x8 vv = *reinterpret_cast<const s16x8*>(&vb[(size_t)d * NTOK + nb + oc * 8]);
      float ls = 0.f;
#pragma unroll
      for (int j = 0; j < 8; ++j) {
        float pv = __expf(b2f((unsigned short)kv[j]) - km);
        kt[d][oc * 8 + j] = pv;
        ls += pv;
        vt[d][oc * 8 + j] = b2f((unsigned short)vv[j]);
      }
      psum[it] += ls;
    }
    __syncthreads();
#pragma unroll 8
    for (int t = 0; t < 256; ++t) {
      float k0 = kt[d2][t], k1 = kt[d2 + 1][t];
      float v0 = vt[e2][t], v1 = vt[e2 + 1][t];
      acc[0][0] += k0 * v0; acc[0][1] += k0 * v1;
      acc[1][0] += k1 * v0; acc[1][1] += k1 * v1;
    }
  }
  // S partials: reduce within each 32-thread d-group
#pragma unroll
  for (int it = 0; it < 4; ++it) {
    float v = psum[it];
    v += __shfl_xor(v, 1); v += __shfl_xor(v, 2); v += __shfl_xor(v, 4);
    v += __shfl_xor(v, 8); v += __shfl_xor(v, 16);
    if ((tid & 31) == 0) {
      int d = (tid >> 5) + it * 8;
      atomicAdd(&Ssum[rbase + d], v);
    }
  }
  float* cb = ctx + (size_t)bh * 1024;
  atomicAdd(&cb[(d2)     * 32 + e2],     acc[0][0]);
  atomicAdd(&cb[(d2)     * 32 + e2 + 1], acc[0][1]);
  atomicAdd(&cb[(d2 + 1) * 32 + e2],     acc[1][0]);
  atomicAdd(&cb[(d2 + 1) * 32 + e2 + 1], acc[1][1]);
}

// ------------------------------------------------------------------
// K5: wctx_b[b][o][h*32+d] = bf16( (1/S[b,h,d]) * sum_e wout[o][h*32+e]*ctx~[b][h][d][e] )
// ------------------------------------------------------------------
__global__ __launch_bounds__(256) void make_wctx(const float* __restrict__ wout,
                                                 const float* __restrict__ ctx,
                                                 const float* __restrict__ Ssum,
                                                 unsigned short* __restrict__ wctxb) {
  int o = blockIdx.x, b = blockIdx.y;
  int tid = threadIdx.x;
  int h = tid >> 5, d = tid & 31;
  const float* cb = ctx + ((size_t)(b * 8 + h)) * 1024 + d * 32;
  const float* wr = wout + (size_t)o * 256 + h * 32;
  float s = 0.f;
#pragma unroll
  for (int e = 0; e < 32; ++e) s += wr[e] * cb[e];
  s *= (1.f / Ssum[b * 256 + tid]);
  wctxb[((size_t)b * 256 + o) * 256 + tid] = f2b(s);
}

// ------------------------------------------------------------------
// K6: out = wctxb @ softmax_d(qT) + bias + x.  Block = (b, 128n), all 256 o
// in 2 passes; q softmax staged once into LDS; barrier-free K loop.
// ------------------------------------------------------------------
__global__ __launch_bounds__(256) void out_gemm(const unsigned short* __restrict__ wctxb,
                                                const unsigned short* __restrict__ qT,
                                                const float* __restrict__ bout,
                                                const float* __restrict__ x,
                                                float* __restrict__ out) {
  __shared__ unsigned short Bs[128 * 256];    // 64KB [n][c] swizzled
  int bid = blockIdx.x;
  int L = (bid & 7) * 128 + (bid >> 3);       // 1024 = 8*128
  int b = L >> 8, ntile = L & 255;
  int n0 = ntile * 128;
  int tid = threadIdx.x;
  int w = tid >> 6, l = tid & 63;
  int hi = l >> 4, lo = l & 15;
  int wo = w >> 1, wn = w & 1;

  // stage softmax(q): 1024 tasks = 128n x 8h
  const unsigned short* qb = qT + ((size_t)(b * NTOK + n0)) * 256;
#pragma unroll
  for (int t2 = 0; t2 < 4; ++t2) {
    int idx = tid + t2 * 256;
    int n = idx >> 3, h = idx & 7;
    const unsigned short* qr = qb + (size_t)n * 256 + h * 32;
    float v[32];
#pragma unroll
    for (int q2 = 0; q2 < 4; ++q2) {
      s16x8 r = *reinterpret_cast<const s16x8*>(&qr[q2 * 8]);
#pragma unroll
      for (int i = 0; i < 8; ++i) v[q2 * 8 + i] = b2f((unsigned short)r[i]);
    }
    float m = v[0];
#pragma unroll
    for (int i = 1; i < 32; ++i) m = fmaxf(m, v[i]);
    float ssum = 0.f;
#pragma unroll
    for (int i = 0; i < 32; ++i) { v[i] = __expf(v[i] - m); ssum += v[i]; }
    float rr = 1.f / ssum;
#pragma unroll
    for (int q2 = 0; q2 < 4; ++q2) {
      s16x8 pk;
#pragma unroll
      for (int i = 0; i < 8; ++i) pk[i] = (short)f2b(v[q2 * 8 + i] * rr);
      int phys = (h * 4 + q2) ^ (n & 7);
      *reinterpret_cast<s16x8*>(&Bs[n * 256 + phys * 8]) = pk;
    }
  }
  __syncthreads();

  const float* xb = x + (size_t)b * 256 * NTOK;
  for (int p = 0; p < 2; ++p) {
    f32x4 acc[4][4];
#pragma unroll
    for (int s = 0; s < 4; ++s)
#pragma unroll
      for (int nt = 0; nt < 4; ++nt) acc[s][nt] = (f32x4){0.f, 0.f, 0.f, 0.f};

    const unsigned short* Ab = wctxb + ((size_t)(b * 256 + p * 128 + wo * 64)) * 256;
#pragma unroll
    for (int t = 0; t < 8; ++t) {
      s16x8 af[4], bf[4];
#pragma unroll
      for (int s = 0; s < 4; ++s)
        af[s] = *reinterpret_cast<const s16x8*>(&Ab[(size_t)(s * 16 + lo) * 256 + t * 32 + hi * 8]);
#pragma unroll
      for (int nt = 0; nt < 4; ++nt) {
        int r = wn * 64 + nt * 16 + lo;
        int phys = (t * 4 + hi) ^ (r & 7);
        bf[nt] = *reinterpret_cast<const s16x8*>(&Bs[r * 256 + phys * 8]);
      }
#pragma unroll
      for (int s = 0; s < 4; ++s)
#pragma unroll
        for (int nt = 0; nt < 4; ++nt)
          acc[s][nt] = __builtin_amdgcn_mfma_f32_16x16x32_bf16(af[s], bf[nt], acc[s][nt], 0, 0, 0);
    }
#pragma unroll
    for (int s = 0; s < 4; ++s)
#pragma unroll
      for (int i = 0; i < 4; ++i) {
        int o = p * 128 + wo * 64 + s * 16 + hi * 4 + i;
        float bo = bout[o];
#pragma unroll
        for (int nt = 0; nt < 4; ++nt) {
          int nn = n0 + wn * 64 + nt * 16 + lo;
          out[((size_t)b * 256 + o) * NTOK + nn] = acc[s][nt][i] + bo + xb[(size_t)o * NTOK + nn];
        }
      }
  }
}

// ------------------------------------------------------------------
extern "C" void kernel_launch(void* const* d_in, const int* in_sizes, int n_in,
                              void* d_out, int out_size, void* d_ws, size_t ws_size,
                              hipStream_t stream) {
  const float* x     = (const float*)d_in[0];
  const float* gamma = (const float*)d_in[1];
  const float* beta  = (const float*)d_in[2];
  const float* wqkv  = (const float*)d_in[3];
  const float* wout  = (const float*)d_in[4];
  const float* bout  = (const float*)d_in[5];
  float* out = (float*)d_out;

  if (ws_size < WS_NEEDED) return;

  char* ws = (char*)d_ws;
  float* gstat        = (float*)(ws + OFF_GSTAT);
  unsigned int* kmk   = (unsigned int*)(ws + OFF_KMK);
  float* Ssum         = (float*)(ws + OFF_SSUM);
  float* ctx          = (float*)(ws + OFF_CTX);
  unsigned short* wctxb = (unsigned short*)(ws + OFF_WCTXB);
  float* biasp        = (float*)(ws + OFF_BIASP);
  unsigned short* Wp  = (unsigned short*)(ws + OFF_WP);
  unsigned short* xT  = (unsigned short*)(ws + OFF_XT);
  unsigned short* qT  = (unsigned short*)(ws + OFF_QT);
  unsigned short* kvb = (unsigned short*)(ws + OFF_KVB);

  // zero: gstat, kmk (0 < all encoded floats), Ssum, ctx
  hipMemsetAsync(ws, 0, OFF_CTX + 131072u, stream);

  gn_fused  <<<dim3(512, 4), 256, 0, stream>>>(x, gstat, xT);
  fold_w    <<<dim3(768, 4), 256, 0, stream>>>(wqkv, gamma, beta, gstat, Wp, biasp);
  qkv_gemm  <<<2048, 256, 0, stream>>>(Wp, biasp, xT, qT, kvb, kmk);
  context_partial<<<dim3(32, 32), 256, 0, stream>>>(kvb, kmk, ctx, Ssum);
  make_wctx <<<dim3(256, 4), 256, 0, stream>>>(wout, ctx, Ssum, wctxb);
  out_gemm  <<<1024, 256, 0, stream>>>(wctxb, qT, bout, x, out);
}

// Round 5
// 332.740 us; speedup vs baseline: 2.0350x; 2.0350x over previous
//
#include <hip/hip_runtime.h>
#include <hip/hip_bf16.h>
#include <math.h>

#define NTOK  32768
#define GNEPS 1e-5f

typedef __attribute__((ext_vector_type(4))) float f32x4;
typedef __attribute__((ext_vector_type(8))) short s16x8;
typedef __attribute__((ext_vector_type(4))) unsigned short u16x4;

__device__ __forceinline__ unsigned short f2b(float f) {
  unsigned int u = __float_as_uint(f);
  unsigned int r = (u + 0x7FFFu + ((u >> 16) & 1u)) >> 16;
  return (unsigned short)r;
}
__device__ __forceinline__ float b2f(unsigned short s) {
  return __uint_as_float(((unsigned int)s) << 16);
}
// order-preserving float<->uint for atomicMax
__device__ __forceinline__ unsigned int fenc(float f) {
  unsigned int u = __float_as_uint(f);
  return (u & 0x80000000u) ? ~u : (u | 0x80000000u);
}
__device__ __forceinline__ float fdec(unsigned int k) {
  unsigned int u = (k & 0x80000000u) ? (k ^ 0x80000000u) : ~k;
  return __uint_as_float(u);
}

__device__ __forceinline__ void stage16(const unsigned short* g, unsigned short* ldsChunkBase, int lane) {
#if __has_builtin(__builtin_amdgcn_global_load_lds)
  __builtin_amdgcn_global_load_lds((const __attribute__((address_space(1))) void*)g,
                                   (__attribute__((address_space(3))) void*)ldsChunkBase, 16, 0, 0);
#else
  *(s16x8*)((char*)ldsChunkBase + lane * 16) = *(const s16x8*)g;
#endif
}

// ---- workspace layout (bytes) ----
#define OFF_GSTAT   0u                // 32 f32
#define OFF_KMK     128u              // 1024 u32 encoded k row max
#define OFF_SSUM    4224u             // 1024 f32 k-softmax denominators
#define OFF_CTX     8320u             // 4*8*32*32 f32 = 131072 (unnormalized)
#define OFF_WCTXB   139392u           // 4*256*256 bf16 = 524288
#define OFF_BIASP   663680u           // 4*768 f32 = 12288
#define OFF_WP      675968u           // 4*768*256 bf16 = 1572864
#define OFF_XT      2248832u          // 4*32768*256 bf16 = 67108864 (raw x, [n][c])
#define OFF_QT      69357696u         // 4*32768*256 bf16 = 67108864
#define OFF_KVB     136466560u        // 4*512*32768 bf16 = 134217728
#define WS_NEEDED   (OFF_KVB + 134217728ull)

// ------------------------------------------------------------------
// K1: fused GN stats + raw-x bf16 cast + transpose -> xT [b][n][c]
// ------------------------------------------------------------------
__global__ __launch_bounds__(256) void gn_fused(const float* __restrict__ x,
                                                float* __restrict__ gstat,
                                                unsigned short* __restrict__ xT) {
  __shared__ unsigned short s1[256 * 68];
  __shared__ float rs[4][4], rq[4][4];
  int b = blockIdx.y;
  int n0 = blockIdx.x * 64;
  int tid = threadIdx.x;
  const float* xb = x + (size_t)b * 256 * NTOK;
  float s[4] = {0.f, 0.f, 0.f, 0.f}, sq[4] = {0.f, 0.f, 0.f, 0.f};
#pragma unroll
  for (int it = 0; it < 16; ++it) {
    int idx = tid + it * 256;          // 4096 = 256c x 16 quads
    int c = idx >> 4, q = idx & 15;
    f32x4 v = *reinterpret_cast<const f32x4*>(&xb[(size_t)c * NTOK + n0 + q * 4]);
    const int g = it >> 2;             // compile-time group
    s[g]  += v.x + v.y + v.z + v.w;
    sq[g] += v.x * v.x + v.y * v.y + v.z * v.z + v.w * v.w;
    u16x4 o = { f2b(v.x), f2b(v.y), f2b(v.z), f2b(v.w) };
    *reinterpret_cast<u16x4*>(&s1[c * 68 + q * 4]) = o;
  }
  int lane = tid & 63, w = tid >> 6;
#pragma unroll
  for (int g = 0; g < 4; ++g) {
    float a = s[g], bq = sq[g];
    for (int o = 32; o > 0; o >>= 1) { a += __shfl_down(a, o); bq += __shfl_down(bq, o); }
    if (lane == 0) { rs[w][g] = a; rq[w][g] = bq; }
  }
  __syncthreads();
  if (tid < 8) {
    int g = tid >> 1, part = tid & 1;
    float v = part ? (rq[0][g] + rq[1][g] + rq[2][g] + rq[3][g])
                   : (rs[0][g] + rs[1][g] + rs[2][g] + rs[3][g]);
    atomicAdd(&gstat[2 * (b * 4 + g) + part], v);
  }
#pragma unroll
  for (int it = 0; it < 8; ++it) {
    int task = tid + it * 256;         // 2048 = 64n x 32 octets
    int n = task >> 5, oc = task & 31;
    s16x8 pk;
#pragma unroll
    for (int i = 0; i < 8; ++i) pk[i] = (short)s1[(oc * 8 + i) * 68 + n];
    *reinterpret_cast<s16x8*>(&xT[((size_t)(b * NTOK + n0 + n)) * 256 + oc * 8]) = pk;
  }
}

// ------------------------------------------------------------------
// K2: finalize stats + fold GN into weights
// ------------------------------------------------------------------
__global__ __launch_bounds__(256) void fold_w(const float* __restrict__ wqkv,
                                              const float* __restrict__ gamma,
                                              const float* __restrict__ beta,
                                              const float* __restrict__ gstat,
                                              unsigned short* __restrict__ Wp,
                                              float* __restrict__ biasp) {
  int o = blockIdx.x, b = blockIdx.y;
  int c = threadIdx.x;
  int g = c >> 6;
  const float cnt = 64.f * (float)NTOK;
  float mu  = gstat[2 * (b * 4 + g)] / cnt;
  float var = gstat[2 * (b * 4 + g) + 1] / cnt - mu * mu;
  float rsig = rsqrtf(var + GNEPS);
  float wv = wqkv[(size_t)o * 256 + c];
  float A = gamma[c] * rsig;
  float Bc = beta[c] - mu * A;
  Wp[((size_t)b * 768 + o) * 256 + c] = f2b(wv * A);
  float t = wv * Bc;
  int lane = c & 63, w = c >> 6;
  for (int off = 32; off > 0; off >>= 1) t += __shfl_down(t, off);
  __shared__ float red[4];
  if (lane == 0) red[w] = t;
  __syncthreads();
  if (c == 0) biasp[b * 768 + o] = red[0] + red[1] + red[2] + red[3];
}

// ------------------------------------------------------------------
// K3: qkv GEMM, 256x128 tile (o x n), 512 thr = 8 waves (4 o-groups x 2 n).
// m97 2-barrier loop: A and B both via global_load_lds (pre-swizzled src),
// BK=64, 4 K-steps. Block is purely q (ot=0), k (ot=1) or v (ot=2).
// Epilogue: bias; q -> qT[n][o] transpose; k/v -> kvb[row][n]; fused k-max.
// ------------------------------------------------------------------
__global__ __launch_bounds__(512, 4) void qkv_gemm(const unsigned short* __restrict__ Wp,
                                                   const float* __restrict__ biasp,
                                                   const unsigned short* __restrict__ xT,
                                                   unsigned short* __restrict__ qT,
                                                   unsigned short* __restrict__ kvb,
                                                   unsigned int* __restrict__ kmk) {
  __shared__ unsigned short smem[24576];   // 48KB: As [0,16384), Bs [16384,24576); epilogue bounce aliases
  unsigned short* As = smem;               // 256 rows x 64c
  unsigned short* Bs = smem + 16384;       // 128 rows x 64c
  int bid = blockIdx.x;
  int L = (bid & 7) * 384 + (bid >> 3);    // chunked XCD swizzle (3072 = 8*384)
  int ot = L % 3;                          // q/k/v — adjacent L share (b,nt) => same XCD L2
  int t2 = L / 3;
  int b = t2 & 3, nt = t2 >> 2;
  int n0 = nt * 128;
  int tid = threadIdx.x;
  int w = tid >> 6, l = tid & 63;
  int hi = (l >> 4) & 3, lo = l & 15;
  int wo = w >> 1, wn = w & 1;
  int lr = l >> 3, lj = l & 7;
  int srcj = lj ^ lr;                      // pre-swizzled source slot (rows 8-aligned per chunk)
  const unsigned short* Abase = Wp + ((size_t)(b * 768 + ot * 256)) * 256;
  const unsigned short* Bbase = xT + ((size_t)(b * NTOK + n0)) * 256;

  f32x4 acc[4][4];
#pragma unroll
  for (int s = 0; s < 4; ++s)
#pragma unroll
    for (int n = 0; n < 4; ++n) acc[s][n] = (f32x4){0.f, 0.f, 0.f, 0.f};

  for (int c0 = 0; c0 < 256; c0 += 64) {
    __syncthreads();
#pragma unroll
    for (int q = 0; q < 4; ++q) {          // A: 32 chunks of 1KB
      int chunk = w * 4 + q; int row = chunk * 8 + lr;
      stage16(Abase + (size_t)row * 256 + c0 + srcj * 8, As + chunk * 512, l);
    }
#pragma unroll
    for (int q = 0; q < 2; ++q) {          // B: 16 chunks
      int chunk = w * 2 + q; int row = chunk * 8 + lr;
      stage16(Bbase + (size_t)row * 256 + c0 + srcj * 8, Bs + chunk * 512, l);
    }
    __syncthreads();
#pragma unroll
    for (int t = 0; t < 2; ++t) {
      s16x8 af[4], bf[4];
#pragma unroll
      for (int s = 0; s < 4; ++s) {
        int row = wo * 64 + s * 16 + lo;
        int phys = (t * 4 + hi) ^ (row & 7);
        af[s] = *reinterpret_cast<const s16x8*>(&As[row * 64 + phys * 8]);
      }
#pragma unroll
      for (int n = 0; n < 4; ++n) {
        int row = wn * 64 + n * 16 + lo;
        int phys = (t * 4 + hi) ^ (row & 7);
        bf[n] = *reinterpret_cast<const s16x8*>(&Bs[row * 64 + phys * 8]);
      }
#pragma unroll
      for (int s = 0; s < 4; ++s)
#pragma unroll
        for (int n = 0; n < 4; ++n)
          acc[s][n] = __builtin_amdgcn_mfma_f32_16x16x32_bf16(af[s], bf[n], acc[s][n], 0, 0, 0);
    }
  }

  // bias add
#pragma unroll
  for (int s = 0; s < 4; ++s)
#pragma unroll
    for (int i = 0; i < 4; ++i) {
      float bv = biasp[b * 768 + ot * 256 + wo * 64 + s * 16 + hi * 4 + i];
#pragma unroll
      for (int n = 0; n < 4; ++n) acc[s][n][i] += bv;
    }

  // fused k row-max (ot==1): reduce over n-frags + 16 lo lanes, atomicMax
  if (ot == 1) {
#pragma unroll
    for (int s = 0; s < 4; ++s)
#pragma unroll
      for (int i = 0; i < 4; ++i) {
        float m = fmaxf(fmaxf(acc[s][0][i], acc[s][1][i]), fmaxf(acc[s][2][i], acc[s][3][i]));
        m = fmaxf(m, __shfl_xor(m, 1));
        m = fmaxf(m, __shfl_xor(m, 2));
        m = fmaxf(m, __shfl_xor(m, 4));
        m = fmaxf(m, __shfl_xor(m, 8));
        if (lo == 0)
          atomicMax(&kmk[b * 256 + wo * 64 + s * 16 + hi * 4 + i], fenc(m));
      }
  }

  // ---- epilogue (bounce aliases smem) ----
  if (ot == 0) {
    // q: transpose -> qT[n][o], 2 rounds over wn halves; bounce [64n][264]
    for (int r = 0; r < 2; ++r) {
      __syncthreads();
      if (wn == r) {
#pragma unroll
        for (int s = 0; s < 4; ++s)
#pragma unroll
          for (int n = 0; n < 4; ++n)
#pragma unroll
            for (int i = 0; i < 4; ++i) {
              int o_l = wo * 64 + s * 16 + hi * 4 + i;   // 0..255
              int n_l = n * 16 + lo;                     // 0..63
              smem[n_l * 264 + o_l] = f2b(acc[s][n][i]);
            }
      }
      __syncthreads();
#pragma unroll
      for (int it = 0; it < 4; ++it) {
        int task = tid + it * 512;                        // 2048 = 64n x 32 slots
        int n_l = task >> 5, j = task & 31;
        s16x8 v = *reinterpret_cast<const s16x8*>(&smem[n_l * 264 + j * 8]);
        *reinterpret_cast<s16x8*>(&qT[((size_t)(b * NTOK + n0 + r * 64 + n_l)) * 256 + j * 8]) = v;
      }
    }
  } else {
    // k/v: [row][n], 2 rounds over wo pairs; bounce [128o][136]
    int vbase = (ot == 1) ? 0 : 256;
    for (int r = 0; r < 2; ++r) {
      __syncthreads();
      if ((wo >> 1) == r) {
#pragma unroll
        for (int s = 0; s < 4; ++s)
#pragma unroll
          for (int n = 0; n < 4; ++n)
#pragma unroll
            for (int i = 0; i < 4; ++i) {
              int o_l = (wo & 1) * 64 + s * 16 + hi * 4 + i;  // 0..127
              int n_l = wn * 64 + n * 16 + lo;                // 0..127
              smem[o_l * 136 + n_l] = f2b(acc[s][n][i]);
            }
      }
      __syncthreads();
#pragma unroll
      for (int it = 0; it < 4; ++it) {
        int task = tid + it * 512;                        // 2048 = 128o x 16 slots
        int o_l = task >> 4, j = task & 15;
        s16x8 v = *reinterpret_cast<const s16x8*>(&smem[o_l * 136 + j * 8]);
        int row = vbase + r * 128 + o_l;
        *reinterpret_cast<s16x8*>(&kvb[((size_t)(b * 512 + row)) * NTOK + n0 + j * 8]) = v;
      }
    }
  }
}

// ------------------------------------------------------------------
// K4: ctx~ += sum_n exp(k-kmax)[d][n] * v[e][n];  Ssum += sum_n exp
// ------------------------------------------------------------------
__global__ __launch_bounds__(256) void context_partial(const unsigned short* __restrict__ kvb,
                                                       const unsigned int* __restrict__ kmk,
                                                       float* __restrict__ ctx,
                                                       float* __restrict__ Ssum) {
  int bh = blockIdx.y;
  int b = bh >> 3, h = bh & 7;
  int n0 = blockIdx.x * 1024;
  const unsigned short* kb = kvb + ((size_t)(b * 512) + h * 32) * NTOK;
  const unsigned short* vb = kvb + ((size_t)(b * 512) + 256 + h * 32) * NTOK;
  __shared__ float kt[32][260];
  __shared__ float vt[32][260];
  int tid = threadIdx.x;
  int d2 = (tid >> 4) * 2;
  int e2 = (tid & 15) * 2;
  int rbase = b * 256 + h * 32;
  float acc[2][2] = {};
  float psum[4] = {0.f, 0.f, 0.f, 0.f};
  for (int sub = 0; sub < 4; ++sub) {
    int nb = n0 + sub * 256;
    __syncthreads();
#pragma unroll
    for (int it = 0; it < 4; ++it) {
      int u = tid + it * 256;
      int d = u >> 5, oc = u & 31;
      float km = fdec(kmk[rbase + d]);
      s16x8 kv = *reinterpret_cast<const s16x8*>(&kb[(size_t)d * NTOK + nb + oc * 8]);
      s16x8 vv = *reinterpret_cast<const s16x8*>(&vb[(size_t)d * NTOK + nb + oc * 8]);
      float ls = 0.f;
#pragma unroll
      for (int j = 0; j < 8; ++j) {
        float pv = __expf(b2f((unsigned short)kv[j]) - km);
        kt[d][oc * 8 + j] = pv;
        ls += pv;
        vt[d][oc * 8 + j] = b2f((unsigned short)vv[j]);
      }
      psum[it] += ls;
    }
    __syncthreads();
#pragma unroll 8
    for (int t = 0; t < 256; ++t) {
      float k0 = kt[d2][t], k1 = kt[d2 + 1][t];
      float v0 = vt[e2][t], v1 = vt[e2 + 1][t];
      acc[0][0] += k0 * v0; acc[0][1] += k0 * v1;
      acc[1][0] += k1 * v0; acc[1][1] += k1 * v1;
    }
  }
#pragma unroll
  for (int it = 0; it < 4; ++it) {
    float v = psum[it];
    v += __shfl_xor(v, 1); v += __shfl_xor(v, 2); v += __shfl_xor(v, 4);
    v += __shfl_xor(v, 8); v += __shfl_xor(v, 16);
    if ((tid & 31) == 0) {
      int d = (tid >> 5) + it * 8;
      atomicAdd(&Ssum[rbase + d], v);
    }
  }
  float* cb = ctx + (size_t)bh * 1024;
  atomicAdd(&cb[(d2)     * 32 + e2],     acc[0][0]);
  atomicAdd(&cb[(d2)     * 32 + e2 + 1], acc[0][1]);
  atomicAdd(&cb[(d2 + 1) * 32 + e2],     acc[1][0]);
  atomicAdd(&cb[(d2 + 1) * 32 + e2 + 1], acc[1][1]);
}

// ------------------------------------------------------------------
// K5: wctx_b = bf16( (1/Ssum) * wout @ ctx~ )
// ------------------------------------------------------------------
__global__ __launch_bounds__(256) void make_wctx(const float* __restrict__ wout,
                                                 const float* __restrict__ ctx,
                                                 const float* __restrict__ Ssum,
                                                 unsigned short* __restrict__ wctxb) {
  int o = blockIdx.x, b = blockIdx.y;
  int tid = threadIdx.x;
  int h = tid >> 5, d = tid & 31;
  const float* cb = ctx + ((size_t)(b * 8 + h)) * 1024 + d * 32;
  const float* wr = wout + (size_t)o * 256 + h * 32;
  float s = 0.f;
#pragma unroll
  for (int e = 0; e < 32; ++e) s += wr[e] * cb[e];
  s *= (1.f / Ssum[b * 256 + tid]);
  wctxb[((size_t)b * 256 + o) * 256 + tid] = f2b(s);
}

// ------------------------------------------------------------------
// K6: out = wctxb @ softmax_d(qT) + bias + x.  (round-3 proven structure)
// ------------------------------------------------------------------
__global__ __launch_bounds__(256) void out_gemm(const unsigned short* __restrict__ wctxb,
                                                const unsigned short* __restrict__ qT,
                                                const float* __restrict__ bout,
                                                const float* __restrict__ x,
                                                float* __restrict__ out) {
  __shared__ unsigned short As[8192];       // [128o][64] swizzled
  __shared__ unsigned short Bs[128 * 68];   // [128n][68] padded, swizzled
  int bid = blockIdx.x;
  int L = (bid & 7) * 256 + (bid >> 3);     // 2048 = 8*256
  int b = L / 512; int rem = L % 512; int ot = rem >> 8; int ntile = rem & 255;
  int n0 = ntile * 128;
  int tid = threadIdx.x;
  int w = tid >> 6, l = tid & 63;
  int wo = w >> 1, wn = w & 1;
  int lr = l >> 3, lj = l & 7;
  int srcj = lj ^ lr;
  const unsigned short* Abase = wctxb + ((size_t)(b * 256 + ot * 128)) * 256;
  const unsigned short* qbase = qT + ((size_t)(b * NTOK + n0)) * 256;

  f32x4 acc[4][4];
#pragma unroll
  for (int s = 0; s < 4; ++s)
#pragma unroll
    for (int n = 0; n < 4; ++n) acc[s][n] = (f32x4){0.f, 0.f, 0.f, 0.f};

  for (int c0 = 0; c0 < 256; c0 += 64) {
    __syncthreads();
#pragma unroll
    for (int q = 0; q < 4; ++q) {
      int chunk = w * 4 + q; int row = chunk * 8 + lr;
      stage16(Abase + (size_t)row * 256 + c0 + srcj * 8, As + chunk * 512, l);
    }
    // B: fused q-softmax staging. n = tid>>1, head-half = tid&1 (2 heads per 64c)
    {
      int n = tid >> 1, hl = tid & 1;
      const unsigned short* qr = qbase + (size_t)n * 256 + c0 + hl * 32;
      float v[32];
#pragma unroll
      for (int q2 = 0; q2 < 4; ++q2) {
        s16x8 r = *reinterpret_cast<const s16x8*>(&qr[q2 * 8]);
#pragma unroll
        for (int i = 0; i < 8; ++i) v[q2 * 8 + i] = b2f((unsigned short)r[i]);
      }
      float m = v[0];
#pragma unroll
      for (int i = 1; i < 32; ++i) m = fmaxf(m, v[i]);
      float ssum = 0.f;
#pragma unroll
      for (int i = 0; i < 32; ++i) { v[i] = __expf(v[i] - m); ssum += v[i]; }
      float rr = 1.f / ssum;
#pragma unroll
      for (int q2 = 0; q2 < 4; ++q2) {
        s16x8 pk;
#pragma unroll
        for (int i = 0; i < 8; ++i) pk[i] = (short)f2b(v[q2 * 8 + i] * rr);
        int phys = (hl * 4 + q2) ^ (n & 7);
        *reinterpret_cast<s16x8*>(&Bs[n * 68 + phys * 8]) = pk;
      }
    }
    __syncthreads();
#pragma unroll
    for (int t = 0; t < 2; ++t) {
      s16x8 af[4], bf[4];
#pragma unroll
      for (int s = 0; s < 4; ++s) {
        int row = wo * 64 + s * 16 + (l & 15);
        int phys = (t * 4 + (l >> 4)) ^ (row & 7);
        af[s] = *reinterpret_cast<const s16x8*>(&As[row * 64 + phys * 8]);
      }
#pragma unroll
      for (int n = 0; n < 4; ++n) {
        int row = wn * 64 + n * 16 + (l & 15);
        int phys = (t * 4 + (l >> 4)) ^ (row & 7);
        bf[n] = *reinterpret_cast<const s16x8*>(&Bs[row * 68 + phys * 8]);
      }
#pragma unroll
      for (int s = 0; s < 4; ++s)
#pragma unroll
        for (int n = 0; n < 4; ++n)
          acc[s][n] = __builtin_amdgcn_mfma_f32_16x16x32_bf16(af[s], bf[n], acc[s][n], 0, 0, 0);
    }
  }

  const float* xb = x + (size_t)b * 256 * NTOK;
#pragma unroll
  for (int s = 0; s < 4; ++s)
#pragma unroll
    for (int i = 0; i < 4; ++i) {
      int o = ot * 128 + wo * 64 + s * 16 + (l >> 4) * 4 + i;
      float bo = bout[o];
#pragma unroll
      for (int n = 0; n < 4; ++n) {
        int nn = n0 + wn * 64 + n * 16 + (l & 15);
        out[((size_t)b * 256 + o) * NTOK + nn] = acc[s][n][i] + bo + xb[(size_t)o * NTOK + nn];
      }
    }
}

// ------------------------------------------------------------------
extern "C" void kernel_launch(void* const* d_in, const int* in_sizes, int n_in,
                              void* d_out, int out_size, void* d_ws, size_t ws_size,
                              hipStream_t stream) {
  const float* x     = (const float*)d_in[0];
  const float* gamma = (const float*)d_in[1];
  const float* beta  = (const float*)d_in[2];
  const float* wqkv  = (const float*)d_in[3];
  const float* wout  = (const float*)d_in[4];
  const float* bout  = (const float*)d_in[5];
  float* out = (float*)d_out;

  if (ws_size < WS_NEEDED) return;

  char* ws = (char*)d_ws;
  float* gstat        = (float*)(ws + OFF_GSTAT);
  unsigned int* kmk   = (unsigned int*)(ws + OFF_KMK);
  float* Ssum         = (float*)(ws + OFF_SSUM);
  float* ctx          = (float*)(ws + OFF_CTX);
  unsigned short* wctxb = (unsigned short*)(ws + OFF_WCTXB);
  float* biasp        = (float*)(ws + OFF_BIASP);
  unsigned short* Wp  = (unsigned short*)(ws + OFF_WP);
  unsigned short* xT  = (unsigned short*)(ws + OFF_XT);
  unsigned short* qT  = (unsigned short*)(ws + OFF_QT);
  unsigned short* kvb = (unsigned short*)(ws + OFF_KVB);

  // zero: gstat, kmk (0 < all encoded floats), Ssum, ctx
  hipMemsetAsync(ws, 0, OFF_CTX + 131072u, stream);

  gn_fused  <<<dim3(512, 4), 256, 0, stream>>>(x, gstat, xT);
  fold_w    <<<dim3(768, 4), 256, 0, stream>>>(wqkv, gamma, beta, gstat, Wp, biasp);
  qkv_gemm  <<<3072, 512, 0, stream>>>(Wp, biasp, xT, qT, kvb, kmk);
  context_partial<<<dim3(32, 32), 256, 0, stream>>>(kvb, kmk, ctx, Ssum);
  make_wctx <<<dim3(256, 4), 256, 0, stream>>>(wout, ctx, Ssum, wctxb);
  out_gemm  <<<2048, 256, 0, stream>>>(wctxb, qT, bout, x, out);
}